// Round 15
// baseline (1367.612 us; speedup 1.0000x reference)
//
#include <hip/hip_runtime.h>
#include <hip/hip_bf16.h>
#include <math.h>

// GPT forward. V=32000 L=6 H=16 D=1024 S=512 B=4, DK=64, DF=4096.
// Round 15: fix gemm_lm LDS swizzle (r14 bug: p(row)=row&3 gave 4-way
// conflicts at 64B row stride; correct is p(row)=(row>>1)&3 -> 2-way=free).
#define V_SIZE 32000
#define L_NUM 6
#define H_NUM 16
#define D_MODEL 1024
#define S_LEN 512
#define B_SZ 4
#define DF_DIM 4096
#define ROWS (B_SZ * S_LEN)   // 2048
#define QKV_N (3 * D_MODEL)   // 3072
#define KVBLK 64
#define NJOB 12               // split-KV jobs per (b,h)

typedef unsigned short u16;
typedef __attribute__((ext_vector_type(8))) short short8v;   // 8 bf16
typedef __attribute__((ext_vector_type(4))) float f32x4;

__device__ __forceinline__ float b2f(u16 b) {
  union { float f; unsigned u; } c; c.u = ((unsigned)b) << 16; return c.f;
}
__device__ __forceinline__ u16 f2b(float f) {
  __hip_bfloat16 h = __float2bfloat16(f);
  union { __hip_bfloat16 h; u16 u; } c; c.h = h; return c.u;
}
__device__ __forceinline__ void g2l16(const void* g, void* l) {
  __builtin_amdgcn_global_load_lds(
      (const __attribute__((address_space(1))) void*)g,
      (__attribute__((address_space(3))) void*)l, 16, 0, 0);
}

// ---------------- embedding + sinusoidal PE (fp32 out) ----------------
__global__ __launch_bounds__(256) void embed_kernel(
    const int* __restrict__ x, const float* __restrict__ tok_emb,
    float* __restrict__ h) {
  int row = blockIdx.x;
  int s = row % S_LEN;
  int tok = x[row];
  const float* te = tok_emb + (size_t)tok * D_MODEL;
  float* hr = h + (size_t)row * D_MODEL;
  float pos = (float)s;
  const float c = 9.210340371976184f / (float)D_MODEL;  // ln(10000)/D
#pragma unroll
  for (int i = 0; i < D_MODEL / 256; ++i) {
    int d = threadIdx.x + i * 256;
    float freq = expf(-(float)(d & ~1) * c);
    float ang = pos * freq;
    float pe = (d & 1) ? cosf(ang) : sinf(ang);
    hr[d] = te[d] + pe;
  }
}

// ---------------- layernorm: wave per row, float4 loads, bf16 out ----------------
__global__ __launch_bounds__(256) void layernorm_kernel(
    const float* __restrict__ in, const float* __restrict__ g,
    const float* __restrict__ b, u16* __restrict__ out) {
  const int row = blockIdx.x * 4 + (threadIdx.x >> 6);
  const int lane = threadIdx.x & 63;
  const float4* xr = (const float4*)(in + (size_t)row * D_MODEL);
  float4 v[4];
  float s1 = 0.f, s2 = 0.f;
#pragma unroll
  for (int i = 0; i < 4; ++i) {
    float4 t = xr[lane + i * 64];
    v[i] = t;
    s1 += t.x + t.y + t.z + t.w;
    s2 += t.x * t.x + t.y * t.y + t.z * t.z + t.w * t.w;
  }
#pragma unroll
  for (int off = 32; off; off >>= 1) {
    s1 += __shfl_xor(s1, off, 64);
    s2 += __shfl_xor(s2, off, 64);
  }
  const float mu = s1 * (1.0f / D_MODEL);
  const float var = s2 * (1.0f / D_MODEL) - mu * mu;
  const float rstd = rsqrtf(var + 1e-5f);
  u16* orow = out + (size_t)row * D_MODEL;
#pragma unroll
  for (int i = 0; i < 4; ++i) {
    const int d = (lane + i * 64) * 4;
    const float4 gv = *(const float4*)&g[d];
    const float4 bv = *(const float4*)&b[d];
    u16 o0 = f2b((v[i].x - mu) * rstd * gv.x + bv.x);
    u16 o1 = f2b((v[i].y - mu) * rstd * gv.y + bv.y);
    u16 o2 = f2b((v[i].z - mu) * rstd * gv.z + bv.z);
    u16 o3 = f2b((v[i].w - mu) * rstd * gv.w + bv.w);
    uint2 pk;
    pk.x = (unsigned)o0 | ((unsigned)o1 << 16);
    pk.y = (unsigned)o2 | ((unsigned)o3 << 16);
    *(uint2*)&orow[d] = pk;
  }
}

// ---------------- batched transpose: ALL weights in one launch ----------------
__global__ __launch_bounds__(256) void transpose_all(
    const float* __restrict__ wq, const float* __restrict__ wk,
    const float* __restrict__ wv, const float* __restrict__ wo,
    const float* __restrict__ w1, const float* __restrict__ w2,
    const float* __restrict__ lm_w,
    u16* __restrict__ wqkvT, u16* __restrict__ woT,
    u16* __restrict__ w1T, u16* __restrict__ w2T, u16* __restrict__ lmT) {
  const size_t DD = (size_t)D_MODEL * D_MODEL;
  const size_t DDF = (size_t)D_MODEL * DF_DIM;
  const long QS = (long)QKV_N * D_MODEL;
  int gid = blockIdx.x;
  const float* src;
  u16* dst;
  int K, N, kt, nt;
  if (gid < 12288) {
    const int l = gid / 2048, rjob = gid % 2048;
    const int which = rjob / 512, t = rjob % 512;
    kt = t % 16; nt = t / 16;
    K = D_MODEL; N = D_MODEL;
    src = (which == 0 ? wq : which == 1 ? wk : which == 2 ? wv : wo) + l * DD;
    dst = (which < 3) ? (wqkvT + l * QS + which * DD) : (woT + l * DD);
  } else if (gid < 24576) {
    const int idx = gid - 12288;
    const int l = idx / 2048, t = idx % 2048;
    kt = t % 16; nt = t / 16;
    K = D_MODEL; N = DF_DIM;
    src = w1 + l * DDF; dst = w1T + l * DDF;
  } else if (gid < 36864) {
    const int idx = gid - 24576;
    const int l = idx / 2048, t = idx % 2048;
    kt = t % 64; nt = t / 64;
    K = DF_DIM; N = D_MODEL;
    src = w2 + l * DDF; dst = w2T + l * DDF;
  } else {
    const int idx = gid - 36864;
    kt = idx % 16; nt = idx / 16;
    K = D_MODEL; N = V_SIZE;
    src = lm_w; dst = lmT;
  }
  __shared__ float t[64][33];
  const int n0 = nt * 32, k0 = kt * 64;
  const int tx = threadIdx.x & 31, ty = threadIdx.x >> 5;   // ty 0..7
#pragma unroll
  for (int i = 0; i < 64; i += 8)
    t[ty + i][tx] = src[(size_t)(k0 + ty + i) * N + n0 + tx];
  __syncthreads();
#pragma unroll
  for (int j = 0; j < 32; j += 8) {
    const int n = ty + j;
    u16 lo = f2b(t[2 * tx][n]);
    u16 hi = f2b(t[2 * tx + 1][n]);
    *(unsigned*)&dst[(size_t)(n0 + n) * K + k0 + 2 * tx] =
        (unsigned)lo | ((unsigned)hi << 16);
  }
}

// ---------------- pack bq|bk|bv -> [L][3072] ----------------
__global__ __launch_bounds__(256) void pack_qkv_bias(
    const float* __restrict__ bq, const float* __restrict__ bk,
    const float* __restrict__ bv, float* __restrict__ out) {
  int i = blockIdx.x * 256 + threadIdx.x;   // 0 .. L*3072-1
  int l = i / QKV_N, j = i % QKV_N;
  float v = (j < D_MODEL) ? bq[l * D_MODEL + j]
          : (j < 2 * D_MODEL) ? bk[l * D_MODEL + j - D_MODEL]
          : bv[l * D_MODEL + j - 2 * D_MODEL];
  out[i] = v;
}

// ---------------- bf16 MFMA GEMM (2-phase, BK=64, XOR-swizzled LDS) ----------------
template <int TM, int OUT_MODE, bool GELU_ACT, int SPLITK>
__global__ __launch_bounds__(256) void gemm_bf16(
    const u16* __restrict__ A, const u16* __restrict__ Bt,
    const float* __restrict__ bias, float* __restrict__ Cf,
    u16* __restrict__ Cb, int M, int N, int K) {
  constexpr int MF = TM / 32;        // A-frags per wave
  constexpr int AINSTS = TM / 32;    // A g2l16 per wave per K-tile (8 rows each)
  __shared__ __align__(16) u16 As[2][TM * 64];
  __shared__ __align__(16) u16 Bs[2][128 * 64];
  const int tid = threadIdx.x;
  const int wid = tid >> 6;
  const int lane = tid & 63;
  const int wr = wid >> 1, wc = wid & 1;
  const int nwg = gridDim.x;
  const int id = blockIdx.x;
  const int q = nwg >> 3, r = nwg & 7;
  const int xcd = id & 7, i0 = id >> 3;
  const int swz = (xcd < r ? xcd * (q + 1) : r * (q + 1) + (xcd - r) * q) + i0;
  const int kh = (SPLITK > 1) ? (swz & (SPLITK - 1)) : 0;
  const int rest = (SPLITK > 1) ? (swz >> 1) : swz;
  const int gm = M / TM;
  const int bm = rest % gm, bn = rest / gm;
  const int Ksub = K / SPLITK;
  const int rowi = lane >> 3;                   // 0..7 within an 8-row inst
  const int gsw = ((lane & 7) ^ rowi) * 8;      // pre-swizzled k-group
  const u16* Ag = A + (size_t)(bm * TM + wid * (TM / 4) + rowi) * K + kh * Ksub + gsw;
  const u16* Bg = Bt + (size_t)(bn * 128 + wid * 32 + rowi) * K + kh * Ksub + gsw;
  auto stage = [&](int buf, int k0) {
#pragma unroll
    for (int i = 0; i < AINSTS; ++i)
      g2l16(Ag + k0 + (size_t)(8 * i) * K, As[buf] + wid * (TM / 4) * 64 + i * 512);
#pragma unroll
    for (int i = 0; i < 4; ++i)
      g2l16(Bg + k0 + (size_t)(8 * i) * K, Bs[buf] + wid * 2048 + i * 512);
  };
  f32x4 acc[MF][4] = {};
  const int fr = lane & 15;
  const int hi = lane >> 4;
  stage(0, 0);
  __syncthreads();
  for (int k0 = 0; k0 < Ksub; k0 += 64) {
    const int cur = (k0 >> 6) & 1;
    if (k0 + 64 < Ksub) stage(cur ^ 1, k0 + 64);
    short8v a[MF][2], b[4][2];
#pragma unroll
    for (int m = 0; m < MF; ++m)
#pragma unroll
      for (int kk = 0; kk < 2; ++kk) {
        const int g = (kk * 4 + hi) ^ (fr & 7);
        a[m][kk] = *(const short8v*)&As[cur][(wr * (TM / 2) + m * 16 + fr) * 64 + g * 8];
      }
#pragma unroll
    for (int n = 0; n < 4; ++n)
#pragma unroll
      for (int kk = 0; kk < 2; ++kk) {
        const int g = (kk * 4 + hi) ^ (fr & 7);
        b[n][kk] = *(const short8v*)&Bs[cur][(wc * 64 + n * 16 + fr) * 64 + g * 8];
      }
    __builtin_amdgcn_s_setprio(1);
#pragma unroll
    for (int kk = 0; kk < 2; ++kk)
#pragma unroll
      for (int m = 0; m < MF; ++m)
#pragma unroll
        for (int n = 0; n < 4; ++n)
          acc[m][n] = __builtin_amdgcn_mfma_f32_16x16x32_bf16(a[m][kk], b[n][kk], acc[m][n], 0, 0, 0);
    __builtin_amdgcn_s_setprio(0);
    __syncthreads();   // drains next-tile stage + barrier
  }
  const int row0 = bm * TM + wr * (TM / 2) + hi * 4;
  const int col0 = bn * 128 + wc * 64 + fr;
#pragma unroll
  for (int m = 0; m < MF; ++m) {
#pragma unroll
    for (int n = 0; n < 4; ++n) {
      const int col = col0 + n * 16;
      float bv = (OUT_MODE == 2) ? 0.f : bias[col];
      if (SPLITK > 1 && kh != 0) bv = 0.f;
#pragma unroll
      for (int r2 = 0; r2 < 4; ++r2) {
        const int row = row0 + m * 16 + r2;
        float v = acc[m][n][r2] + bv;
        if (GELU_ACT) v = 0.5f * v * (1.0f + erff(v * 0.70710678118f));
        size_t idx = (size_t)row * N + col;
        if (OUT_MODE == 0) Cb[idx] = f2b(v);
        else if (OUT_MODE == 1) {
          if (SPLITK > 1) atomicAdd(&Cf[idx], v);
          else Cf[idx] += v;
        } else Cf[idx] = v;
      }
    }
  }
}

// ---------------- LM head: 128x256 tile, BK=32, 48KB LDS, 2 blocks/CU ----------------
// Swizzle (fixed r15): p(row)=(row>>1)&3. Store: lane slot (lane&3) loads
// global group (lane&3)^((lane>>3)&3). Read: g = hi ^ ((fr>>1)&3) -> <=2-way
// bank aliasing (free).
__global__ __launch_bounds__(512, 4) void gemm_lm(
    const u16* __restrict__ A, const u16* __restrict__ Bt,
    float* __restrict__ C, int M, int N, int K) {
  __shared__ __align__(16) u16 smem[24576];   // 48 KB: A 2x8KB | B 2x16KB
  const int tid = threadIdx.x, wid = tid >> 6, lane = tid & 63;
  const int wm = wid >> 2, wn = wid & 3;
  const int fr = lane & 15, hi = lane >> 4;
  const int T = K / 32;   // 32
  const int nwg = gridDim.x, id = blockIdx.x;
  const int q = nwg >> 3, r = nwg & 7;
  const int xcd = id & 7, i0 = id >> 3;
  const int swz = (xcd < r ? xcd * (q + 1) : r * (q + 1) + (xcd - r) * q) + i0;
  const int gm = M / 128;   // 16
  const int bm = swz % gm, bn = swz / gm;
  const int rowA0 = bm * 128, rowB0 = bn * 256;
  const int gsw = ((lane & 3) ^ ((lane >> 3) & 3)) * 8;  // pre-swizzled col-group
  const u16* Ag = A + (size_t)(rowA0 + wid * 16 + (lane >> 2)) * K + gsw;
  const u16* Bg = Bt + (size_t)(rowB0 + wid * 32 + (lane >> 2)) * K + gsw;
  auto stage = [&](int buf, int t) {
    g2l16(Ag + t * 32, smem + buf * 4096 + wid * 512);
    g2l16(Bg + t * 32, smem + 8192 + buf * 8192 + wid * 1024);
    g2l16(Bg + t * 32 + (size_t)16 * K, smem + 8192 + buf * 8192 + wid * 1024 + 512);
  };
  f32x4 acc[4][4] = {};
  stage(0, 0);
  asm volatile("s_waitcnt vmcnt(0)" ::: "memory");
  __builtin_amdgcn_s_barrier();
  for (int t = 0; t < T; ++t) {
    const int cur = t & 1, nxt = cur ^ 1;
    short8v a[4], b[4];
    const int g = hi ^ ((fr >> 1) & 3);
    // phase 0: A (all 4 m-frags) + B cols 0..31
#pragma unroll
    for (int m = 0; m < 4; ++m)
      a[m] = *(const short8v*)&smem[cur * 4096 + (wm * 64 + m * 16 + fr) * 32 + g * 8];
#pragma unroll
    for (int n = 0; n < 2; ++n)
      b[n] = *(const short8v*)&smem[8192 + cur * 8192 + (wn * 64 + n * 16 + fr) * 32 + g * 8];
    if (t + 1 < T) stage(nxt, t + 1);
    __builtin_amdgcn_s_barrier();
    asm volatile("s_waitcnt lgkmcnt(0)" ::: "memory");
    __builtin_amdgcn_sched_barrier(0);
    __builtin_amdgcn_s_setprio(1);
#pragma unroll
    for (int m = 0; m < 4; ++m)
#pragma unroll
      for (int n = 0; n < 2; ++n)
        acc[m][n] = __builtin_amdgcn_mfma_f32_16x16x32_bf16(a[m], b[n], acc[m][n], 0, 0, 0);
    __builtin_amdgcn_s_setprio(0);
    __builtin_amdgcn_s_barrier();
    // phase 1: B cols 32..63 (A held in regs)
#pragma unroll
    for (int n = 2; n < 4; ++n)
      b[n] = *(const short8v*)&smem[8192 + cur * 8192 + (wn * 64 + n * 16 + fr) * 32 + g * 8];
    __builtin_amdgcn_s_barrier();
    asm volatile("s_waitcnt lgkmcnt(0)" ::: "memory");
    __builtin_amdgcn_sched_barrier(0);
    __builtin_amdgcn_s_setprio(1);
#pragma unroll
    for (int m = 0; m < 4; ++m)
#pragma unroll
      for (int n = 2; n < 4; ++n)
        acc[m][n] = __builtin_amdgcn_mfma_f32_16x16x32_bf16(a[m], b[n], acc[m][n], 0, 0, 0);
    __builtin_amdgcn_s_setprio(0);
    if (t + 1 < T) {
      asm volatile("s_waitcnt vmcnt(0)" ::: "memory");
      __builtin_amdgcn_s_barrier();
    }
  }
  // ---- epilogue: 4 LDS-staged chunks of 32 rows x 256 cols f32 ----
  float* lf = (float*)smem;   // 32 KB
#pragma unroll
  for (int c = 0; c < 4; ++c) {
    __syncthreads();
    if (wm == (c >> 1)) {
      const int mbase = (c & 1) * 2;
#pragma unroll
      for (int mm = 0; mm < 2; ++mm)
#pragma unroll
        for (int n = 0; n < 4; ++n)
#pragma unroll
          for (int rr = 0; rr < 4; ++rr)
            lf[(mm * 16 + hi * 4 + rr) * 256 + wn * 64 + n * 16 + fr] =
                acc[mbase + mm][n][rr];
    }
    __syncthreads();
#pragma unroll
    for (int i = 0; i < 4; ++i) {
      const int f = (i * 512 + tid) * 4;
      const int rw = f >> 8, cl = f & 255;
      f32x4 v = *(const f32x4*)&lf[f];
      *(f32x4*)&C[(size_t)(rowA0 + c * 32 + rw) * N + rowB0 + cl] = v;
    }
  }
}

// ---------------- attention: split-KV partial blocks ----------------
__global__ __launch_bounds__(256) void attn_part(
    const u16* __restrict__ qkv, float* __restrict__ Op,
    float* __restrict__ Ml, u16* __restrict__ ctx) {
  __shared__ __align__(16) u16 smem[3 * 64 * 72];   // 27 KB
  u16 (*Qs)[72] = (u16(*)[72])smem;             // [64][72]
  u16 (*Ks)[72] = (u16(*)[72])(smem + 4608);    // [64][72]
  u16 (*Vs)[72] = (u16(*)[72])(smem + 9216);    // [64][72]  V^T: [d][k]
  const int job = blockIdx.x, bh = blockIdx.y;
  constexpr int qt_of[NJOB] = {0, 1, 2, 3, 4, 4, 5, 5, 6, 6, 7, 7};
  constexpr int ch_of[NJOB] = {0, 0, 0, 0, 0, 1, 0, 1, 0, 1, 0, 1};
  const int qt = qt_of[job], ch = ch_of[job];
  const int b = bh >> 4, h = bh & 15;
  const int tid = threadIdx.x, wid = tid >> 6, lane = tid & 63;
  const int fr = lane & 15, ko = (lane >> 4) * 8;
  u16 (*Ps)[72] = (u16(*)[72])(smem + wid * 1152);  // [16][72]/wave, aliases Qs
  const size_t rb = (size_t)b * S_LEN;
  const int q0 = qt * 64;
  const int hq = h * 64;
  const int t_lo = ch * 4;
  const int t_hi = (qt + 1 < t_lo + 4) ? qt + 1 : t_lo + 4;
#pragma unroll
  for (int i = 0; i < 2; ++i) {
    int e = tid + i * 256, r = e >> 3, c = (e & 7) * 8;
    *(short8v*)&Qs[r][c] = *(const short8v*)&qkv[(rb + q0 + r) * QKV_N + hq + c];
  }
  __syncthreads();
  short8v qf[2];
#pragma unroll
  for (int ks = 0; ks < 2; ++ks)
    qf[ks] = *(const short8v*)&Qs[wid * 16 + fr][ks * 32 + ko];
  f32x4 acc_o[4] = {};
  float mrow[4], lrow[4];
#pragma unroll
  for (int r = 0; r < 4; ++r) { mrow[r] = -1e30f; lrow[r] = 0.f; }
  short8v kreg[2], vreg[2];
  auto loadregs = [&](int t) {
    const int k0 = t * KVBLK;
#pragma unroll
    for (int i = 0; i < 2; ++i) {
      const int e = tid + i * 256, rr = e >> 3, cc = (e & 7) * 8;
      kreg[i] = *(const short8v*)&qkv[(rb + k0 + rr) * QKV_N + D_MODEL + hq + cc];
      vreg[i] = *(const short8v*)&qkv[(rb + k0 + rr) * QKV_N + 2 * D_MODEL + hq + cc];
    }
  };
  loadregs(t_lo);
  for (int t = t_lo; t < t_hi; ++t) {
    __syncthreads();   // Ks/Vs reads (prev iter) done
#pragma unroll
    for (int i = 0; i < 2; ++i) {
      const int e = tid + i * 256, rr = e >> 3, cc = (e & 7) * 8;
      *(short8v*)&Ks[rr][cc] = kreg[i];
#pragma unroll
      for (int j = 0; j < 8; ++j) Vs[cc + j][rr] = (u16)vreg[i][j];
    }
    __syncthreads();
    if (t + 1 < t_hi) loadregs(t + 1);   // overlap next loads with compute
    const int k0 = t * KVBLK;
    f32x4 s[4] = {};
    __builtin_amdgcn_s_setprio(1);
#pragma unroll
    for (int n = 0; n < 4; ++n)
#pragma unroll
      for (int ks = 0; ks < 2; ++ks) {
        short8v kf = *(const short8v*)&Ks[n * 16 + fr][ks * 32 + ko];
        s[n] = __builtin_amdgcn_mfma_f32_16x16x32_bf16(qf[ks], kf, s[n], 0, 0, 0);
      }
    __builtin_amdgcn_s_setprio(0);
    const int rbase = q0 + wid * 16 + (lane >> 4) * 4;
#pragma unroll
    for (int r = 0; r < 4; ++r) {
      const int row_g = rbase + r;
      float vmax = -1e30f;
#pragma unroll
      for (int n = 0; n < 4; ++n) {
        float v = s[n][r] * 0.125f;
        if (k0 + n * 16 + fr > row_g) v = -1e30f;
        s[n][r] = v;
        vmax = fmaxf(vmax, v);
      }
#pragma unroll
      for (int off = 1; off < 16; off <<= 1) vmax = fmaxf(vmax, __shfl_xor(vmax, off, 64));
      const float mnew = fmaxf(mrow[r], vmax);
      const float sc = __expf(mrow[r] - mnew);
      mrow[r] = mnew;
      float ssum = 0.f;
#pragma unroll
      for (int n = 0; n < 4; ++n) {
        float p = __expf(s[n][r] - mnew);
        s[n][r] = p;
        ssum += p;
      }
#pragma unroll
      for (int off = 1; off < 16; off <<= 1) ssum += __shfl_xor(ssum, off, 64);
      lrow[r] = lrow[r] * sc + ssum;
#pragma unroll
      for (int n = 0; n < 4; ++n) {
        acc_o[n][r] *= sc;
        Ps[(lane >> 4) * 4 + r][n * 16 + fr] = f2b(s[n][r]);
      }
    }
    __builtin_amdgcn_s_setprio(1);
#pragma unroll
    for (int ks = 0; ks < 2; ++ks) {
      short8v pf = *(const short8v*)&Ps[fr][ks * 32 + ko];
#pragma unroll
      for (int n = 0; n < 4; ++n) {
        short8v vf = *(const short8v*)&Vs[n * 16 + fr][ks * 32 + ko];
        acc_o[n] = __builtin_amdgcn_mfma_f32_16x16x32_bf16(pf, vf, acc_o[n], 0, 0, 0);
      }
    }
    __builtin_amdgcn_s_setprio(0);
  }
  if (qt < 4) {
#pragma unroll
    for (int r = 0; r < 4; ++r) {
      const int row_l = wid * 16 + (lane >> 4) * 4 + r;
      const float inv = 1.0f / lrow[r];
#pragma unroll
      for (int n = 0; n < 4; ++n)
        ctx[(rb + q0 + row_l) * D_MODEL + hq + n * 16 + fr] = f2b(acc_o[n][r] * inv);
    }
  } else {
    const size_t jb = (size_t)(bh * NJOB + job);
#pragma unroll
    for (int r = 0; r < 4; ++r) {
      const int row_l = wid * 16 + (lane >> 4) * 4 + r;
      const size_t base = (jb * 64 + row_l) * 64;
#pragma unroll
      for (int n = 0; n < 4; ++n) Op[base + n * 16 + fr] = acc_o[n][r];
      if (fr == 0) {
        Ml[jb * 128 + row_l * 2] = mrow[r];
        Ml[jb * 128 + row_l * 2 + 1] = lrow[r];
      }
    }
  }
}

// ---------------- attention: combine partials (qt>=4) -> ctx (bf16) ----------------
__global__ __launch_bounds__(256) void attn_combine(
    const float* __restrict__ Op, const float* __restrict__ Ml,
    u16* __restrict__ ctx) {
  const int qt = blockIdx.x + 4, bh = blockIdx.y;
  const int b = bh >> 4, h = bh & 15;
  const int j0 = 4 + blockIdx.x * 2;
  const size_t rb = (size_t)b * S_LEN;
  const int q0 = qt * 64, hq = h * 64;
  const size_t jb1 = (size_t)(bh * NJOB + j0);
  const size_t jb2 = jb1 + 1;
#pragma unroll
  for (int i = 0; i < 4; ++i) {
    const int idx4 = threadIdx.x + i * 256;     // float4 index 0..1023
    const int row = idx4 >> 4, c4 = (idx4 & 15) * 4;
    f32x4 o1 = *(const f32x4*)&Op[(jb1 * 64 + row) * 64 + c4];
    const float m1 = Ml[jb1 * 128 + row * 2], l1 = Ml[jb1 * 128 + row * 2 + 1];
    f32x4 o2 = *(const f32x4*)&Op[(jb2 * 64 + row) * 64 + c4];
    const float m2 = Ml[jb2 * 128 + row * 2], l2 = Ml[jb2 * 128 + row * 2 + 1];
    const float m = fmaxf(m1, m2);
    const float e1 = __expf(m1 - m), e2 = __expf(m2 - m);
    const float inv = 1.0f / (l1 * e1 + l2 * e2);
    float o[4];
#pragma unroll
    for (int j = 0; j < 4; ++j) o[j] = o1[j] * e1 + o2[j] * e2;
    uint2 pk;
    pk.x = (unsigned)f2b(o[0] * inv) | ((unsigned)f2b(o[1] * inv) << 16);
    pk.y = (unsigned)f2b(o[2] * inv) | ((unsigned)f2b(o[3] * inv) << 16);
    *(uint2*)&ctx[(rb + q0 + row) * D_MODEL + hq + c4] = pk;
  }
}

// ---------------- launch ----------------
extern "C" void kernel_launch(void* const* d_in, const int* in_sizes, int n_in,
                              void* d_out, int out_size, void* d_ws, size_t ws_size,
                              hipStream_t stream) {
  const int* x = (const int*)d_in[0];
  const float* tok_emb = (const float*)d_in[1];
  const float* wq = (const float*)d_in[2];
  const float* bq = (const float*)d_in[3];
  const float* wk = (const float*)d_in[4];
  const float* bk = (const float*)d_in[5];
  const float* wv = (const float*)d_in[6];
  const float* bv = (const float*)d_in[7];
  const float* wo = (const float*)d_in[8];
  const float* bo = (const float*)d_in[9];
  const float* ln1_g = (const float*)d_in[10];
  const float* ln1_b = (const float*)d_in[11];
  const float* w1 = (const float*)d_in[12];
  const float* b1 = (const float*)d_in[13];
  const float* w2 = (const float*)d_in[14];
  const float* b2 = (const float*)d_in[15];
  const float* ln2_g = (const float*)d_in[16];
  const float* ln2_b = (const float*)d_in[17];
  const float* lnf_g = (const float*)d_in[18];
  const float* lnf_b = (const float*)d_in[19];
  const float* lm_w = (const float*)d_in[20];

  char* w = (char*)d_ws;
  float* h    = (float*)(w);                      // 8 MB   fp32 residual
  u16*  hn    = (u16*)(w + (8ll << 20));          // 4 MB   bf16 LN out
  u16*  qkvb  = (u16*)(w + (12ll << 20));         // 12 MB  bf16 packed qkv
  u16*  cbuf  = (u16*)(w + (24ll << 20));         // 4 MB   bf16 attn ctx
  u16*  ff    = qkvb;                             // 16 MB  alias qkv+cbuf
  u16*  wqkvT = (u16*)(w + (28ll << 20));         // 36 MB  [L][3072][1024]
  u16*  woT   = (u16*)(w + (64ll << 20));         // 12 MB  [L][1024][1024]
  u16*  w1T   = (u16*)(w + (76ll << 20));         // 48 MB  [L][4096][1024]
  u16*  w2T   = (u16*)(w + (124ll << 20));        // 48 MB  [L][1024][4096]
  u16*  lmT   = (u16*)(w + (172ll << 20));        // 62.5MB [32000][1024]
  float* bqkv = (float*)(w + (235ll << 20));      // 72 KB  [L][3072]
  float* Op   = (float*)(w + (236ll << 20));      // 12 MB  attn partial O
  float* Ml   = (float*)(w + (249ll << 20));      // 0.4 MB attn partial m,l

  transpose_all<<<52864, 256, 0, stream>>>(
      wq, wk, wv, wo, w1, w2, lm_w, wqkvT, woT, w1T, w2T, lmT);
  pack_qkv_bias<<<L_NUM * QKV_N / 256, 256, 0, stream>>>(bq, bk, bv, bqkv);

  embed_kernel<<<ROWS, 256, 0, stream>>>(x, tok_emb, h);

  const size_t DD = (size_t)D_MODEL * D_MODEL;
  const size_t DDF = (size_t)D_MODEL * DF_DIM;
  const long QS = (long)QKV_N * D_MODEL;
  const int nQKV = (ROWS / 64) * (QKV_N / 128);       // 768  (3/CU)
  const int nPRJ = 2 * (ROWS / 64) * (D_MODEL / 128); // 512  (2/CU, split-K)
  const int nFF1 = (ROWS / 64) * (DF_DIM / 128);      // 1024
  const int nFF2 = 2 * (ROWS / 64) * (D_MODEL / 128); // 512  (2/CU, split-K)
  for (int l = 0; l < L_NUM; ++l) {
    layernorm_kernel<<<ROWS / 4, 256, 0, stream>>>(h, ln1_g + l * D_MODEL, ln1_b + l * D_MODEL, hn);
    gemm_bf16<64, 0, false, 1><<<nQKV, 256, 0, stream>>>(
        hn, wqkvT + (size_t)l * QS, bqkv + l * QKV_N, nullptr, qkvb,
        ROWS, QKV_N, D_MODEL);
    attn_part<<<dim3(NJOB, B_SZ * H_NUM), 256, 0, stream>>>(qkvb, Op, Ml, cbuf);
    attn_combine<<<dim3(4, B_SZ * H_NUM), 256, 0, stream>>>(Op, Ml, cbuf);
    gemm_bf16<64, 1, false, 2><<<nPRJ, 256, 0, stream>>>(
        cbuf, woT + l * DD, bo + l * D_MODEL, h, nullptr, ROWS, D_MODEL, D_MODEL);
    layernorm_kernel<<<ROWS / 4, 256, 0, stream>>>(h, ln2_g + l * D_MODEL, ln2_b + l * D_MODEL, hn);
    gemm_bf16<64, 0, true, 1><<<nFF1, 256, 0, stream>>>(
        hn, w1T + l * DDF, b1 + l * DF_DIM, nullptr, ff, ROWS, DF_DIM, D_MODEL);
    gemm_bf16<64, 1, false, 2><<<nFF2, 256, 0, stream>>>(
        ff, w2T + l * DDF, b2 + l * D_MODEL, h, nullptr, ROWS, D_MODEL, DF_DIM);
  }
  layernorm_kernel<<<ROWS / 4, 256, 0, stream>>>(h, lnf_g, lnf_b, hn);

  const int nLM = (ROWS / 128) * (V_SIZE / 256);   // 16 * 125 = 2000
  gemm_lm<<<nLM, 512, 0, stream>>>(
      hn, lmT, (float*)d_out, ROWS, V_SIZE, D_MODEL);
}

// Round 16
// 1347.046 us; speedup vs baseline: 1.0153x; 1.0153x over previous
//
#include <hip/hip_runtime.h>
#include <hip/hip_bf16.h>
#include <math.h>

// GPT forward. V=32000 L=6 H=16 D=1024 S=512 B=4, DK=64, DF=4096.
// Round 16: revert LM head to the r13 256^2 8-phase counted-vmcnt kernel
// (r14/r15 128x256 BK=32 experiment: per-tile vmcnt(0) drain made it slower
// regardless of occupancy; conflict fix confirmed null on time).
#define V_SIZE 32000
#define L_NUM 6
#define H_NUM 16
#define D_MODEL 1024
#define S_LEN 512
#define B_SZ 4
#define DF_DIM 4096
#define ROWS (B_SZ * S_LEN)   // 2048
#define QKV_N (3 * D_MODEL)   // 3072
#define KVBLK 64
#define NJOB 12               // split-KV jobs per (b,h)

typedef unsigned short u16;
typedef __attribute__((ext_vector_type(8))) short short8v;   // 8 bf16
typedef __attribute__((ext_vector_type(4))) float f32x4;

__device__ __forceinline__ float b2f(u16 b) {
  union { float f; unsigned u; } c; c.u = ((unsigned)b) << 16; return c.f;
}
__device__ __forceinline__ u16 f2b(float f) {
  __hip_bfloat16 h = __float2bfloat16(f);
  union { __hip_bfloat16 h; u16 u; } c; c.h = h; return c.u;
}
__device__ __forceinline__ void g2l16(const void* g, void* l) {
  __builtin_amdgcn_global_load_lds(
      (const __attribute__((address_space(1))) void*)g,
      (__attribute__((address_space(3))) void*)l, 16, 0, 0);
}

// ---------------- embedding + sinusoidal PE (fp32 out) ----------------
__global__ __launch_bounds__(256) void embed_kernel(
    const int* __restrict__ x, const float* __restrict__ tok_emb,
    float* __restrict__ h) {
  int row = blockIdx.x;
  int s = row % S_LEN;
  int tok = x[row];
  const float* te = tok_emb + (size_t)tok * D_MODEL;
  float* hr = h + (size_t)row * D_MODEL;
  float pos = (float)s;
  const float c = 9.210340371976184f / (float)D_MODEL;  // ln(10000)/D
#pragma unroll
  for (int i = 0; i < D_MODEL / 256; ++i) {
    int d = threadIdx.x + i * 256;
    float freq = expf(-(float)(d & ~1) * c);
    float ang = pos * freq;
    float pe = (d & 1) ? cosf(ang) : sinf(ang);
    hr[d] = te[d] + pe;
  }
}

// ---------------- layernorm: wave per row, float4 loads, bf16 out ----------------
__global__ __launch_bounds__(256) void layernorm_kernel(
    const float* __restrict__ in, const float* __restrict__ g,
    const float* __restrict__ b, u16* __restrict__ out) {
  const int row = blockIdx.x * 4 + (threadIdx.x >> 6);
  const int lane = threadIdx.x & 63;
  const float4* xr = (const float4*)(in + (size_t)row * D_MODEL);
  float4 v[4];
  float s1 = 0.f, s2 = 0.f;
#pragma unroll
  for (int i = 0; i < 4; ++i) {
    float4 t = xr[lane + i * 64];
    v[i] = t;
    s1 += t.x + t.y + t.z + t.w;
    s2 += t.x * t.x + t.y * t.y + t.z * t.z + t.w * t.w;
  }
#pragma unroll
  for (int off = 32; off; off >>= 1) {
    s1 += __shfl_xor(s1, off, 64);
    s2 += __shfl_xor(s2, off, 64);
  }
  const float mu = s1 * (1.0f / D_MODEL);
  const float var = s2 * (1.0f / D_MODEL) - mu * mu;
  const float rstd = rsqrtf(var + 1e-5f);
  u16* orow = out + (size_t)row * D_MODEL;
#pragma unroll
  for (int i = 0; i < 4; ++i) {
    const int d = (lane + i * 64) * 4;
    const float4 gv = *(const float4*)&g[d];
    const float4 bv = *(const float4*)&b[d];
    u16 o0 = f2b((v[i].x - mu) * rstd * gv.x + bv.x);
    u16 o1 = f2b((v[i].y - mu) * rstd * gv.y + bv.y);
    u16 o2 = f2b((v[i].z - mu) * rstd * gv.z + bv.z);
    u16 o3 = f2b((v[i].w - mu) * rstd * gv.w + bv.w);
    uint2 pk;
    pk.x = (unsigned)o0 | ((unsigned)o1 << 16);
    pk.y = (unsigned)o2 | ((unsigned)o3 << 16);
    *(uint2*)&orow[d] = pk;
  }
}

// ---------------- batched transpose: ALL weights in one launch ----------------
__global__ __launch_bounds__(256) void transpose_all(
    const float* __restrict__ wq, const float* __restrict__ wk,
    const float* __restrict__ wv, const float* __restrict__ wo,
    const float* __restrict__ w1, const float* __restrict__ w2,
    const float* __restrict__ lm_w,
    u16* __restrict__ wqkvT, u16* __restrict__ woT,
    u16* __restrict__ w1T, u16* __restrict__ w2T, u16* __restrict__ lmT) {
  const size_t DD = (size_t)D_MODEL * D_MODEL;
  const size_t DDF = (size_t)D_MODEL * DF_DIM;
  const long QS = (long)QKV_N * D_MODEL;
  int gid = blockIdx.x;
  const float* src;
  u16* dst;
  int K, N, kt, nt;
  if (gid < 12288) {
    const int l = gid / 2048, rjob = gid % 2048;
    const int which = rjob / 512, t = rjob % 512;
    kt = t % 16; nt = t / 16;
    K = D_MODEL; N = D_MODEL;
    src = (which == 0 ? wq : which == 1 ? wk : which == 2 ? wv : wo) + l * DD;
    dst = (which < 3) ? (wqkvT + l * QS + which * DD) : (woT + l * DD);
  } else if (gid < 24576) {
    const int idx = gid - 12288;
    const int l = idx / 2048, t = idx % 2048;
    kt = t % 16; nt = t / 16;
    K = D_MODEL; N = DF_DIM;
    src = w1 + l * DDF; dst = w1T + l * DDF;
  } else if (gid < 36864) {
    const int idx = gid - 24576;
    const int l = idx / 2048, t = idx % 2048;
    kt = t % 64; nt = t / 64;
    K = DF_DIM; N = D_MODEL;
    src = w2 + l * DDF; dst = w2T + l * DDF;
  } else {
    const int idx = gid - 36864;
    kt = idx % 16; nt = idx / 16;
    K = D_MODEL; N = V_SIZE;
    src = lm_w; dst = lmT;
  }
  __shared__ float t[64][33];
  const int n0 = nt * 32, k0 = kt * 64;
  const int tx = threadIdx.x & 31, ty = threadIdx.x >> 5;   // ty 0..7
#pragma unroll
  for (int i = 0; i < 64; i += 8)
    t[ty + i][tx] = src[(size_t)(k0 + ty + i) * N + n0 + tx];
  __syncthreads();
#pragma unroll
  for (int j = 0; j < 32; j += 8) {
    const int n = ty + j;
    u16 lo = f2b(t[2 * tx][n]);
    u16 hi = f2b(t[2 * tx + 1][n]);
    *(unsigned*)&dst[(size_t)(n0 + n) * K + k0 + 2 * tx] =
        (unsigned)lo | ((unsigned)hi << 16);
  }
}

// ---------------- pack bq|bk|bv -> [L][3072] ----------------
__global__ __launch_bounds__(256) void pack_qkv_bias(
    const float* __restrict__ bq, const float* __restrict__ bk,
    const float* __restrict__ bv, float* __restrict__ out) {
  int i = blockIdx.x * 256 + threadIdx.x;   // 0 .. L*3072-1
  int l = i / QKV_N, j = i % QKV_N;
  float v = (j < D_MODEL) ? bq[l * D_MODEL + j]
          : (j < 2 * D_MODEL) ? bk[l * D_MODEL + j - D_MODEL]
          : bv[l * D_MODEL + j - 2 * D_MODEL];
  out[i] = v;
}

// ---------------- bf16 MFMA GEMM (2-phase, BK=64, XOR-swizzled LDS) ----------------
template <int TM, int OUT_MODE, bool GELU_ACT, int SPLITK>
__global__ __launch_bounds__(256) void gemm_bf16(
    const u16* __restrict__ A, const u16* __restrict__ Bt,
    const float* __restrict__ bias, float* __restrict__ Cf,
    u16* __restrict__ Cb, int M, int N, int K) {
  constexpr int MF = TM / 32;        // A-frags per wave
  constexpr int AINSTS = TM / 32;    // A g2l16 per wave per K-tile (8 rows each)
  __shared__ __align__(16) u16 As[2][TM * 64];
  __shared__ __align__(16) u16 Bs[2][128 * 64];
  const int tid = threadIdx.x;
  const int wid = tid >> 6;
  const int lane = tid & 63;
  const int wr = wid >> 1, wc = wid & 1;
  const int nwg = gridDim.x;
  const int id = blockIdx.x;
  const int q = nwg >> 3, r = nwg & 7;
  const int xcd = id & 7, i0 = id >> 3;
  const int swz = (xcd < r ? xcd * (q + 1) : r * (q + 1) + (xcd - r) * q) + i0;
  const int kh = (SPLITK > 1) ? (swz & (SPLITK - 1)) : 0;
  const int rest = (SPLITK > 1) ? (swz >> 1) : swz;
  const int gm = M / TM;
  const int bm = rest % gm, bn = rest / gm;
  const int Ksub = K / SPLITK;
  const int rowi = lane >> 3;                   // 0..7 within an 8-row inst
  const int gsw = ((lane & 7) ^ rowi) * 8;      // pre-swizzled k-group
  const u16* Ag = A + (size_t)(bm * TM + wid * (TM / 4) + rowi) * K + kh * Ksub + gsw;
  const u16* Bg = Bt + (size_t)(bn * 128 + wid * 32 + rowi) * K + kh * Ksub + gsw;
  auto stage = [&](int buf, int k0) {
#pragma unroll
    for (int i = 0; i < AINSTS; ++i)
      g2l16(Ag + k0 + (size_t)(8 * i) * K, As[buf] + wid * (TM / 4) * 64 + i * 512);
#pragma unroll
    for (int i = 0; i < 4; ++i)
      g2l16(Bg + k0 + (size_t)(8 * i) * K, Bs[buf] + wid * 2048 + i * 512);
  };
  f32x4 acc[MF][4] = {};
  const int fr = lane & 15;
  const int hi = lane >> 4;
  stage(0, 0);
  __syncthreads();
  for (int k0 = 0; k0 < Ksub; k0 += 64) {
    const int cur = (k0 >> 6) & 1;
    if (k0 + 64 < Ksub) stage(cur ^ 1, k0 + 64);
    short8v a[MF][2], b[4][2];
#pragma unroll
    for (int m = 0; m < MF; ++m)
#pragma unroll
      for (int kk = 0; kk < 2; ++kk) {
        const int g = (kk * 4 + hi) ^ (fr & 7);
        a[m][kk] = *(const short8v*)&As[cur][(wr * (TM / 2) + m * 16 + fr) * 64 + g * 8];
      }
#pragma unroll
    for (int n = 0; n < 4; ++n)
#pragma unroll
      for (int kk = 0; kk < 2; ++kk) {
        const int g = (kk * 4 + hi) ^ (fr & 7);
        b[n][kk] = *(const short8v*)&Bs[cur][(wc * 64 + n * 16 + fr) * 64 + g * 8];
      }
    __builtin_amdgcn_s_setprio(1);
#pragma unroll
    for (int kk = 0; kk < 2; ++kk)
#pragma unroll
      for (int m = 0; m < MF; ++m)
#pragma unroll
        for (int n = 0; n < 4; ++n)
          acc[m][n] = __builtin_amdgcn_mfma_f32_16x16x32_bf16(a[m][kk], b[n][kk], acc[m][n], 0, 0, 0);
    __builtin_amdgcn_s_setprio(0);
    __syncthreads();   // drains next-tile stage + barrier
  }
  const int row0 = bm * TM + wr * (TM / 2) + hi * 4;
  const int col0 = bn * 128 + wc * 64 + fr;
#pragma unroll
  for (int m = 0; m < MF; ++m) {
#pragma unroll
    for (int n = 0; n < 4; ++n) {
      const int col = col0 + n * 16;
      float bv = (OUT_MODE == 2) ? 0.f : bias[col];
      if (SPLITK > 1 && kh != 0) bv = 0.f;
#pragma unroll
      for (int r2 = 0; r2 < 4; ++r2) {
        const int row = row0 + m * 16 + r2;
        float v = acc[m][n][r2] + bv;
        if (GELU_ACT) v = 0.5f * v * (1.0f + erff(v * 0.70710678118f));
        size_t idx = (size_t)row * N + col;
        if (OUT_MODE == 0) Cb[idx] = f2b(v);
        else if (OUT_MODE == 1) {
          if (SPLITK > 1) atomicAdd(&Cf[idx], v);
          else Cf[idx] += v;
        } else Cf[idx] = v;
      }
    }
  }
}

// ---------------- 256^2 8-phase counted-vmcnt GEMM (LM head) ----------------
#define LDA_H(H)                                                            \
  _Pragma("unroll") for (int m = 0; m < 4; ++m)                             \
  _Pragma("unroll") for (int ks = 0; ks < 2; ++ks) {                        \
    const int row_ = wm * 128 + (H)*64 + m * 16 + fr;                       \
    const int g_ = (ks * 4 + hi) ^ (fr & 7);                                \
    a[m][ks] = *(const short8v*)&smem[cur * 16384 + row_ * 64 + g_ * 8];    \
  }
#define LDB_H(H)                                                            \
  _Pragma("unroll") for (int n = 0; n < 2; ++n)                             \
  _Pragma("unroll") for (int ks = 0; ks < 2; ++ks) {                        \
    const int row_ = wn * 64 + (H)*32 + n * 16 + fr;                        \
    const int g_ = (ks * 4 + hi) ^ (fr & 7);                                \
    b[n][ks] = *(const short8v*)&smem[32768 + cur * 16384 + row_ * 64 + g_ * 8]; \
  }
#define MFMA_CLUSTER(QA, QB)                                                \
  __builtin_amdgcn_s_barrier();                                             \
  asm volatile("s_waitcnt lgkmcnt(0)" ::: "memory");                        \
  __builtin_amdgcn_sched_barrier(0);                                        \
  __builtin_amdgcn_s_setprio(1);                                            \
  _Pragma("unroll") for (int ks = 0; ks < 2; ++ks)                          \
  _Pragma("unroll") for (int m = 0; m < 4; ++m)                             \
  _Pragma("unroll") for (int n = 0; n < 2; ++n)                             \
    acc[(QA)*4 + m][(QB)*2 + n] = __builtin_amdgcn_mfma_f32_16x16x32_bf16(  \
        a[m][ks], b[n][ks], acc[(QA)*4 + m][(QB)*2 + n], 0, 0, 0);          \
  __builtin_amdgcn_s_setprio(0);

__global__ __launch_bounds__(512, 2) void gemm256_lm(
    const u16* __restrict__ A, const u16* __restrict__ Bt,
    float* __restrict__ C, int M, int N, int K) {
  extern __shared__ __align__(16) u16 smem[];   // 128 KiB
  const int tid = threadIdx.x, wid = tid >> 6, lane = tid & 63;
  const int wm = wid >> 2, wn = wid & 3;
  const int fr = lane & 15, hi = lane >> 4;
  const int T = K / 64;
  const int nwg = gridDim.x, id = blockIdx.x;
  const int q = nwg >> 3, r = nwg & 7;
  const int xcd = id & 7, i0 = id >> 3;
  const int swz = (xcd < r ? xcd * (q + 1) : r * (q + 1) + (xcd - r) * q) + i0;
  const int gm = M / 256;
  const int bm = swz % gm, bn = swz / gm;
  const int rowA0 = bm * 256, rowB0 = bn * 256;
  const int rowoff = wid * 8 + (lane >> 3);
  const int gsw = ((lane & 7) ^ (lane >> 3)) * 8;   // pre-swizzled source group
  auto stA = [&](int qq, int tt, int bb) {
    g2l16(A + (size_t)(rowA0 + qq * 64 + rowoff) * K + tt * 64 + gsw,
          smem + bb * 16384 + qq * 4096 + wid * 512);
  };
  auto stB = [&](int qq, int tt, int bb) {
    g2l16(Bt + (size_t)(rowB0 + qq * 64 + rowoff) * K + tt * 64 + gsw,
          smem + 32768 + bb * 16384 + qq * 4096 + wid * 512);
  };
  f32x4 acc[8][4] = {};
  stA(0, 0, 0); stA(2, 0, 0);
  stB(0, 0, 0); stB(1, 0, 0); stB(2, 0, 0); stB(3, 0, 0);
  stA(1, 0, 0); stA(3, 0, 0);
  if (T > 1) {
    stA(0, 1, 1); stA(2, 1, 1);
    asm volatile("s_waitcnt vmcnt(2)" ::: "memory");
  } else {
    asm volatile("s_waitcnt vmcnt(0)" ::: "memory");
  }
  __builtin_amdgcn_s_barrier();
  for (int t = 0; t < T; ++t) {
    const int cur = t & 1, nxt = cur ^ 1;
    short8v a[4][2], b[2][2];
    // phase 0: Q(0,0)
    LDA_H(0); LDB_H(0);
    if (t + 1 < T) { stB(0, t + 1, nxt); stB(1, t + 1, nxt); }
    MFMA_CLUSTER(0, 0);
    __builtin_amdgcn_s_barrier();
    // phase 1: Q(0,1) -- A half 0 held in regs
    LDB_H(1);
    if (t + 1 < T) { stB(2, t + 1, nxt); stB(3, t + 1, nxt); }
    MFMA_CLUSTER(0, 1);
    __builtin_amdgcn_s_barrier();
    // phase 2: Q(1,1) -- B half 1 held in regs
    LDA_H(1);
    if (t + 1 < T) { stA(1, t + 1, nxt); stA(3, t + 1, nxt); }
    MFMA_CLUSTER(1, 1);
    __builtin_amdgcn_s_barrier();
    // phase 3: Q(1,0) -- A half 1 held, B half 0 re-read
    LDB_H(0);
    if (t + 2 < T) { stA(0, t + 2, cur); stA(2, t + 2, cur); }
    MFMA_CLUSTER(1, 0);
    if (t + 1 < T) {
      if (t + 2 < T) asm volatile("s_waitcnt vmcnt(2)" ::: "memory");
      else           asm volatile("s_waitcnt vmcnt(0)" ::: "memory");
      __builtin_amdgcn_s_barrier();
    }
  }
  // ---- LDS-staged coalesced epilogue: 2 chunks of 128 rows x 256 cols f32 ----
  float* lf = (float*)smem;
#pragma unroll
  for (int c = 0; c < 2; ++c) {
    __syncthreads();
    if (wm == c) {
#pragma unroll
      for (int m = 0; m < 8; ++m)
#pragma unroll
        for (int n = 0; n < 4; ++n)
#pragma unroll
          for (int rr = 0; rr < 4; ++rr)
            lf[(m * 16 + hi * 4 + rr) * 256 + wn * 64 + n * 16 + fr] =
                acc[m][n][rr];
    }
    __syncthreads();
#pragma unroll
    for (int i = 0; i < 16; ++i) {
      const int f = i * 2048 + tid * 4;
      const int rw = f >> 8, cl = f & 255;
      f32x4 v = *(const f32x4*)&lf[f];
      *(f32x4*)&C[(size_t)(rowA0 + c * 128 + rw) * N + rowB0 + cl] = v;
    }
  }
}

// ---------------- attention: split-KV partial blocks ----------------
__global__ __launch_bounds__(256) void attn_part(
    const u16* __restrict__ qkv, float* __restrict__ Op,
    float* __restrict__ Ml, u16* __restrict__ ctx) {
  __shared__ __align__(16) u16 smem[3 * 64 * 72];   // 27 KB
  u16 (*Qs)[72] = (u16(*)[72])smem;             // [64][72]
  u16 (*Ks)[72] = (u16(*)[72])(smem + 4608);    // [64][72]
  u16 (*Vs)[72] = (u16(*)[72])(smem + 9216);    // [64][72]  V^T: [d][k]
  const int job = blockIdx.x, bh = blockIdx.y;
  constexpr int qt_of[NJOB] = {0, 1, 2, 3, 4, 4, 5, 5, 6, 6, 7, 7};
  constexpr int ch_of[NJOB] = {0, 0, 0, 0, 0, 1, 0, 1, 0, 1, 0, 1};
  const int qt = qt_of[job], ch = ch_of[job];
  const int b = bh >> 4, h = bh & 15;
  const int tid = threadIdx.x, wid = tid >> 6, lane = tid & 63;
  const int fr = lane & 15, ko = (lane >> 4) * 8;
  u16 (*Ps)[72] = (u16(*)[72])(smem + wid * 1152);  // [16][72]/wave, aliases Qs
  const size_t rb = (size_t)b * S_LEN;
  const int q0 = qt * 64;
  const int hq = h * 64;
  const int t_lo = ch * 4;
  const int t_hi = (qt + 1 < t_lo + 4) ? qt + 1 : t_lo + 4;
#pragma unroll
  for (int i = 0; i < 2; ++i) {
    int e = tid + i * 256, r = e >> 3, c = (e & 7) * 8;
    *(short8v*)&Qs[r][c] = *(const short8v*)&qkv[(rb + q0 + r) * QKV_N + hq + c];
  }
  __syncthreads();
  short8v qf[2];
#pragma unroll
  for (int ks = 0; ks < 2; ++ks)
    qf[ks] = *(const short8v*)&Qs[wid * 16 + fr][ks * 32 + ko];
  f32x4 acc_o[4] = {};
  float mrow[4], lrow[4];
#pragma unroll
  for (int r = 0; r < 4; ++r) { mrow[r] = -1e30f; lrow[r] = 0.f; }
  short8v kreg[2], vreg[2];
  auto loadregs = [&](int t) {
    const int k0 = t * KVBLK;
#pragma unroll
    for (int i = 0; i < 2; ++i) {
      const int e = tid + i * 256, rr = e >> 3, cc = (e & 7) * 8;
      kreg[i] = *(const short8v*)&qkv[(rb + k0 + rr) * QKV_N + D_MODEL + hq + cc];
      vreg[i] = *(const short8v*)&qkv[(rb + k0 + rr) * QKV_N + 2 * D_MODEL + hq + cc];
    }
  };
  loadregs(t_lo);
  for (int t = t_lo; t < t_hi; ++t) {
    __syncthreads();   // Ks/Vs reads (prev iter) done
#pragma unroll
    for (int i = 0; i < 2; ++i) {
      const int e = tid + i * 256, rr = e >> 3, cc = (e & 7) * 8;
      *(short8v*)&Ks[rr][cc] = kreg[i];
#pragma unroll
      for (int j = 0; j < 8; ++j) Vs[cc + j][rr] = (u16)vreg[i][j];
    }
    __syncthreads();
    if (t + 1 < t_hi) loadregs(t + 1);   // overlap next loads with compute
    const int k0 = t * KVBLK;
    f32x4 s[4] = {};
    __builtin_amdgcn_s_setprio(1);
#pragma unroll
    for (int n = 0; n < 4; ++n)
#pragma unroll
      for (int ks = 0; ks < 2; ++ks) {
        short8v kf = *(const short8v*)&Ks[n * 16 + fr][ks * 32 + ko];
        s[n] = __builtin_amdgcn_mfma_f32_16x16x32_bf16(qf[ks], kf, s[n], 0, 0, 0);
      }
    __builtin_amdgcn_s_setprio(0);
    const int rbase = q0 + wid * 16 + (lane >> 4) * 4;
#pragma unroll
    for (int r = 0; r < 4; ++r) {
      const int row_g = rbase + r;
      float vmax = -1e30f;
#pragma unroll
      for (int n = 0; n < 4; ++n) {
        float v = s[n][r] * 0.125f;
        if (k0 + n * 16 + fr > row_g) v = -1e30f;
        s[n][r] = v;
        vmax = fmaxf(vmax, v);
      }
#pragma unroll
      for (int off = 1; off < 16; off <<= 1) vmax = fmaxf(vmax, __shfl_xor(vmax, off, 64));
      const float mnew = fmaxf(mrow[r], vmax);
      const float sc = __expf(mrow[r] - mnew);
      mrow[r] = mnew;
      float ssum = 0.f;
#pragma unroll
      for (int n = 0; n < 4; ++n) {
        float p = __expf(s[n][r] - mnew);
        s[n][r] = p;
        ssum += p;
      }
#pragma unroll
      for (int off = 1; off < 16; off <<= 1) ssum += __shfl_xor(ssum, off, 64);
      lrow[r] = lrow[r] * sc + ssum;
#pragma unroll
      for (int n = 0; n < 4; ++n) {
        acc_o[n][r] *= sc;
        Ps[(lane >> 4) * 4 + r][n * 16 + fr] = f2b(s[n][r]);
      }
    }
    __builtin_amdgcn_s_setprio(1);
#pragma unroll
    for (int ks = 0; ks < 2; ++ks) {
      short8v pf = *(const short8v*)&Ps[fr][ks * 32 + ko];
#pragma unroll
      for (int n = 0; n < 4; ++n) {
        short8v vf = *(const short8v*)&Vs[n * 16 + fr][ks * 32 + ko];
        acc_o[n] = __builtin_amdgcn_mfma_f32_16x16x32_bf16(pf, vf, acc_o[n], 0, 0, 0);
      }
    }
    __builtin_amdgcn_s_setprio(0);
  }
  if (qt < 4) {
#pragma unroll
    for (int r = 0; r < 4; ++r) {
      const int row_l = wid * 16 + (lane >> 4) * 4 + r;
      const float inv = 1.0f / lrow[r];
#pragma unroll
      for (int n = 0; n < 4; ++n)
        ctx[(rb + q0 + row_l) * D_MODEL + hq + n * 16 + fr] = f2b(acc_o[n][r] * inv);
    }
  } else {
    const size_t jb = (size_t)(bh * NJOB + job);
#pragma unroll
    for (int r = 0; r < 4; ++r) {
      const int row_l = wid * 16 + (lane >> 4) * 4 + r;
      const size_t base = (jb * 64 + row_l) * 64;
#pragma unroll
      for (int n = 0; n < 4; ++n) Op[base + n * 16 + fr] = acc_o[n][r];
      if (fr == 0) {
        Ml[jb * 128 + row_l * 2] = mrow[r];
        Ml[jb * 128 + row_l * 2 + 1] = lrow[r];
      }
    }
  }
}

// ---------------- attention: combine partials (qt>=4) -> ctx (bf16) ----------------
__global__ __launch_bounds__(256) void attn_combine(
    const float* __restrict__ Op, const float* __restrict__ Ml,
    u16* __restrict__ ctx) {
  const int qt = blockIdx.x + 4, bh = blockIdx.y;
  const int b = bh >> 4, h = bh & 15;
  const int j0 = 4 + blockIdx.x * 2;
  const size_t rb = (size_t)b * S_LEN;
  const int q0 = qt * 64, hq = h * 64;
  const size_t jb1 = (size_t)(bh * NJOB + j0);
  const size_t jb2 = jb1 + 1;
#pragma unroll
  for (int i = 0; i < 4; ++i) {
    const int idx4 = threadIdx.x + i * 256;     // float4 index 0..1023
    const int row = idx4 >> 4, c4 = (idx4 & 15) * 4;
    f32x4 o1 = *(const f32x4*)&Op[(jb1 * 64 + row) * 64 + c4];
    const float m1 = Ml[jb1 * 128 + row * 2], l1 = Ml[jb1 * 128 + row * 2 + 1];
    f32x4 o2 = *(const f32x4*)&Op[(jb2 * 64 + row) * 64 + c4];
    const float m2 = Ml[jb2 * 128 + row * 2], l2 = Ml[jb2 * 128 + row * 2 + 1];
    const float m = fmaxf(m1, m2);
    const float e1 = __expf(m1 - m), e2 = __expf(m2 - m);
    const float inv = 1.0f / (l1 * e1 + l2 * e2);
    float o[4];
#pragma unroll
    for (int j = 0; j < 4; ++j) o[j] = o1[j] * e1 + o2[j] * e2;
    uint2 pk;
    pk.x = (unsigned)f2b(o[0] * inv) | ((unsigned)f2b(o[1] * inv) << 16);
    pk.y = (unsigned)f2b(o[2] * inv) | ((unsigned)f2b(o[3] * inv) << 16);
    *(uint2*)&ctx[(rb + q0 + row) * D_MODEL + hq + c4] = pk;
  }
}

// ---------------- launch ----------------
extern "C" void kernel_launch(void* const* d_in, const int* in_sizes, int n_in,
                              void* d_out, int out_size, void* d_ws, size_t ws_size,
                              hipStream_t stream) {
  const int* x = (const int*)d_in[0];
  const float* tok_emb = (const float*)d_in[1];
  const float* wq = (const float*)d_in[2];
  const float* bq = (const float*)d_in[3];
  const float* wk = (const float*)d_in[4];
  const float* bk = (const float*)d_in[5];
  const float* wv = (const float*)d_in[6];
  const float* bv = (const float*)d_in[7];
  const float* wo = (const float*)d_in[8];
  const float* bo = (const float*)d_in[9];
  const float* ln1_g = (const float*)d_in[10];
  const float* ln1_b = (const float*)d_in[11];
  const float* w1 = (const float*)d_in[12];
  const float* b1 = (const float*)d_in[13];
  const float* w2 = (const float*)d_in[14];
  const float* b2 = (const float*)d_in[15];
  const float* ln2_g = (const float*)d_in[16];
  const float* ln2_b = (const float*)d_in[17];
  const float* lnf_g = (const float*)d_in[18];
  const float* lnf_b = (const float*)d_in[19];
  const float* lm_w = (const float*)d_in[20];

  char* w = (char*)d_ws;
  float* h    = (float*)(w);                      // 8 MB   fp32 residual
  u16*  hn    = (u16*)(w + (8ll << 20));          // 4 MB   bf16 LN out
  u16*  qkvb  = (u16*)(w + (12ll << 20));         // 12 MB  bf16 packed qkv
  u16*  cbuf  = (u16*)(w + (24ll << 20));         // 4 MB   bf16 attn ctx
  u16*  ff    = qkvb;                             // 16 MB  alias qkv+cbuf
  u16*  wqkvT = (u16*)(w + (28ll << 20));         // 36 MB  [L][3072][1024]
  u16*  woT   = (u16*)(w + (64ll << 20));         // 12 MB  [L][1024][1024]
  u16*  w1T   = (u16*)(w + (76ll << 20));         // 48 MB  [L][4096][1024]
  u16*  w2T   = (u16*)(w + (124ll << 20));        // 48 MB  [L][1024][4096]
  u16*  lmT   = (u16*)(w + (172ll << 20));        // 62.5MB [32000][1024]
  float* bqkv = (float*)(w + (235ll << 20));      // 72 KB  [L][3072]
  float* Op   = (float*)(w + (236ll << 20));      // 12 MB  attn partial O
  float* Ml   = (float*)(w + (249ll << 20));      // 0.4 MB attn partial m,l

  transpose_all<<<52864, 256, 0, stream>>>(
      wq, wk, wv, wo, w1, w2, lm_w, wqkvT, woT, w1T, w2T, lmT);
  pack_qkv_bias<<<L_NUM * QKV_N / 256, 256, 0, stream>>>(bq, bk, bv, bqkv);

  embed_kernel<<<ROWS, 256, 0, stream>>>(x, tok_emb, h);

  const size_t DD = (size_t)D_MODEL * D_MODEL;
  const size_t DDF = (size_t)D_MODEL * DF_DIM;
  const long QS = (long)QKV_N * D_MODEL;
  const int nQKV = (ROWS / 64) * (QKV_N / 128);       // 768  (3/CU)
  const int nPRJ = 2 * (ROWS / 64) * (D_MODEL / 128); // 512  (2/CU, split-K)
  const int nFF1 = (ROWS / 64) * (DF_DIM / 128);      // 1024
  const int nFF2 = 2 * (ROWS / 64) * (D_MODEL / 128); // 512  (2/CU, split-K)
  for (int l = 0; l < L_NUM; ++l) {
    layernorm_kernel<<<ROWS / 4, 256, 0, stream>>>(h, ln1_g + l * D_MODEL, ln1_b + l * D_MODEL, hn);
    gemm_bf16<64, 0, false, 1><<<nQKV, 256, 0, stream>>>(
        hn, wqkvT + (size_t)l * QS, bqkv + l * QKV_N, nullptr, qkvb,
        ROWS, QKV_N, D_MODEL);
    attn_part<<<dim3(NJOB, B_SZ * H_NUM), 256, 0, stream>>>(qkvb, Op, Ml, cbuf);
    attn_combine<<<dim3(4, B_SZ * H_NUM), 256, 0, stream>>>(Op, Ml, cbuf);
    gemm_bf16<64, 1, false, 2><<<nPRJ, 256, 0, stream>>>(
        cbuf, woT + l * DD, bo + l * D_MODEL, h, nullptr, ROWS, D_MODEL, D_MODEL);
    layernorm_kernel<<<ROWS / 4, 256, 0, stream>>>(h, ln2_g + l * D_MODEL, ln2_b + l * D_MODEL, hn);
    gemm_bf16<64, 0, true, 1><<<nFF1, 256, 0, stream>>>(
        hn, w1T + l * DDF, b1 + l * DF_DIM, nullptr, ff, ROWS, DF_DIM, D_MODEL);
    gemm_bf16<64, 1, false, 2><<<nFF2, 256, 0, stream>>>(
        ff, w2T + l * DDF, b2 + l * D_MODEL, h, nullptr, ROWS, D_MODEL, DF_DIM);
  }
  layernorm_kernel<<<ROWS / 4, 256, 0, stream>>>(h, lnf_g, lnf_b, hn);

  hipFuncSetAttribute((const void*)gemm256_lm,
                      hipFuncAttributeMaxDynamicSharedMemorySize, 131072);
  const int nLM = (ROWS / 256) * (V_SIZE / 256);   // 8 * 125 = 1000
  gemm256_lm<<<nLM, 512, 131072, stream>>>(
      hn, lmT, (float*)d_out, ROWS, V_SIZE, D_MODEL);
}

// Round 17
// 1261.013 us; speedup vs baseline: 1.0845x; 1.0682x over previous
//
#include <hip/hip_runtime.h>
#include <hip/hip_bf16.h>
#include <math.h>

// GPT forward. V=32000 L=6 H=16 D=1024 S=512 B=4, DK=64, DF=4096.
// Round 17: FF1 -> TM=128 (64x64 wave tile, +50% FLOP per LDS read; 512
// blocks = exactly 2/CU at 64KB LDS). Other GEMMs unchanged (grid fit).
#define V_SIZE 32000
#define L_NUM 6
#define H_NUM 16
#define D_MODEL 1024
#define S_LEN 512
#define B_SZ 4
#define DF_DIM 4096
#define ROWS (B_SZ * S_LEN)   // 2048
#define QKV_N (3 * D_MODEL)   // 3072
#define KVBLK 64
#define NJOB 12               // split-KV jobs per (b,h)

typedef unsigned short u16;
typedef __attribute__((ext_vector_type(8))) short short8v;   // 8 bf16
typedef __attribute__((ext_vector_type(4))) float f32x4;

__device__ __forceinline__ float b2f(u16 b) {
  union { float f; unsigned u; } c; c.u = ((unsigned)b) << 16; return c.f;
}
__device__ __forceinline__ u16 f2b(float f) {
  __hip_bfloat16 h = __float2bfloat16(f);
  union { __hip_bfloat16 h; u16 u; } c; c.h = h; return c.u;
}
__device__ __forceinline__ void g2l16(const void* g, void* l) {
  __builtin_amdgcn_global_load_lds(
      (const __attribute__((address_space(1))) void*)g,
      (__attribute__((address_space(3))) void*)l, 16, 0, 0);
}

// ---------------- embedding + sinusoidal PE (fp32 out) ----------------
__global__ __launch_bounds__(256) void embed_kernel(
    const int* __restrict__ x, const float* __restrict__ tok_emb,
    float* __restrict__ h) {
  int row = blockIdx.x;
  int s = row % S_LEN;
  int tok = x[row];
  const float* te = tok_emb + (size_t)tok * D_MODEL;
  float* hr = h + (size_t)row * D_MODEL;
  float pos = (float)s;
  const float c = 9.210340371976184f / (float)D_MODEL;  // ln(10000)/D
#pragma unroll
  for (int i = 0; i < D_MODEL / 256; ++i) {
    int d = threadIdx.x + i * 256;
    float freq = expf(-(float)(d & ~1) * c);
    float ang = pos * freq;
    float pe = (d & 1) ? cosf(ang) : sinf(ang);
    hr[d] = te[d] + pe;
  }
}

// ---------------- layernorm: wave per row, float4 loads, bf16 out ----------------
__global__ __launch_bounds__(256) void layernorm_kernel(
    const float* __restrict__ in, const float* __restrict__ g,
    const float* __restrict__ b, u16* __restrict__ out) {
  const int row = blockIdx.x * 4 + (threadIdx.x >> 6);
  const int lane = threadIdx.x & 63;
  const float4* xr = (const float4*)(in + (size_t)row * D_MODEL);
  float4 v[4];
  float s1 = 0.f, s2 = 0.f;
#pragma unroll
  for (int i = 0; i < 4; ++i) {
    float4 t = xr[lane + i * 64];
    v[i] = t;
    s1 += t.x + t.y + t.z + t.w;
    s2 += t.x * t.x + t.y * t.y + t.z * t.z + t.w * t.w;
  }
#pragma unroll
  for (int off = 32; off; off >>= 1) {
    s1 += __shfl_xor(s1, off, 64);
    s2 += __shfl_xor(s2, off, 64);
  }
  const float mu = s1 * (1.0f / D_MODEL);
  const float var = s2 * (1.0f / D_MODEL) - mu * mu;
  const float rstd = rsqrtf(var + 1e-5f);
  u16* orow = out + (size_t)row * D_MODEL;
#pragma unroll
  for (int i = 0; i < 4; ++i) {
    const int d = (lane + i * 64) * 4;
    const float4 gv = *(const float4*)&g[d];
    const float4 bv = *(const float4*)&b[d];
    u16 o0 = f2b((v[i].x - mu) * rstd * gv.x + bv.x);
    u16 o1 = f2b((v[i].y - mu) * rstd * gv.y + bv.y);
    u16 o2 = f2b((v[i].z - mu) * rstd * gv.z + bv.z);
    u16 o3 = f2b((v[i].w - mu) * rstd * gv.w + bv.w);
    uint2 pk;
    pk.x = (unsigned)o0 | ((unsigned)o1 << 16);
    pk.y = (unsigned)o2 | ((unsigned)o3 << 16);
    *(uint2*)&orow[d] = pk;
  }
}

// ---------------- batched transpose: ALL weights in one launch ----------------
__global__ __launch_bounds__(256) void transpose_all(
    const float* __restrict__ wq, const float* __restrict__ wk,
    const float* __restrict__ wv, const float* __restrict__ wo,
    const float* __restrict__ w1, const float* __restrict__ w2,
    const float* __restrict__ lm_w,
    u16* __restrict__ wqkvT, u16* __restrict__ woT,
    u16* __restrict__ w1T, u16* __restrict__ w2T, u16* __restrict__ lmT) {
  const size_t DD = (size_t)D_MODEL * D_MODEL;
  const size_t DDF = (size_t)D_MODEL * DF_DIM;
  const long QS = (long)QKV_N * D_MODEL;
  int gid = blockIdx.x;
  const float* src;
  u16* dst;
  int K, N, kt, nt;
  if (gid < 12288) {
    const int l = gid / 2048, rjob = gid % 2048;
    const int which = rjob / 512, t = rjob % 512;
    kt = t % 16; nt = t / 16;
    K = D_MODEL; N = D_MODEL;
    src = (which == 0 ? wq : which == 1 ? wk : which == 2 ? wv : wo) + l * DD;
    dst = (which < 3) ? (wqkvT + l * QS + which * DD) : (woT + l * DD);
  } else if (gid < 24576) {
    const int idx = gid - 12288;
    const int l = idx / 2048, t = idx % 2048;
    kt = t % 16; nt = t / 16;
    K = D_MODEL; N = DF_DIM;
    src = w1 + l * DDF; dst = w1T + l * DDF;
  } else if (gid < 36864) {
    const int idx = gid - 24576;
    const int l = idx / 2048, t = idx % 2048;
    kt = t % 64; nt = t / 64;
    K = DF_DIM; N = D_MODEL;
    src = w2 + l * DDF; dst = w2T + l * DDF;
  } else {
    const int idx = gid - 36864;
    kt = idx % 16; nt = idx / 16;
    K = D_MODEL; N = V_SIZE;
    src = lm_w; dst = lmT;
  }
  __shared__ float t[64][33];
  const int n0 = nt * 32, k0 = kt * 64;
  const int tx = threadIdx.x & 31, ty = threadIdx.x >> 5;   // ty 0..7
#pragma unroll
  for (int i = 0; i < 64; i += 8)
    t[ty + i][tx] = src[(size_t)(k0 + ty + i) * N + n0 + tx];
  __syncthreads();
#pragma unroll
  for (int j = 0; j < 32; j += 8) {
    const int n = ty + j;
    u16 lo = f2b(t[2 * tx][n]);
    u16 hi = f2b(t[2 * tx + 1][n]);
    *(unsigned*)&dst[(size_t)(n0 + n) * K + k0 + 2 * tx] =
        (unsigned)lo | ((unsigned)hi << 16);
  }
}

// ---------------- pack bq|bk|bv -> [L][3072] ----------------
__global__ __launch_bounds__(256) void pack_qkv_bias(
    const float* __restrict__ bq, const float* __restrict__ bk,
    const float* __restrict__ bv, float* __restrict__ out) {
  int i = blockIdx.x * 256 + threadIdx.x;   // 0 .. L*3072-1
  int l = i / QKV_N, j = i % QKV_N;
  float v = (j < D_MODEL) ? bq[l * D_MODEL + j]
          : (j < 2 * D_MODEL) ? bk[l * D_MODEL + j - D_MODEL]
          : bv[l * D_MODEL + j - 2 * D_MODEL];
  out[i] = v;
}

// ---------------- bf16 MFMA GEMM (2-phase, BK=64, XOR-swizzled LDS) ----------------
// TM=64: 32x64 wave tile, 32KB LDS, 3+/CU. TM=128: 64x64 wave tile (+50%
// FLOP per LDS read), 64KB LDS, 2/CU.
template <int TM, int OUT_MODE, bool GELU_ACT, int SPLITK>
__global__ __launch_bounds__(256) void gemm_bf16(
    const u16* __restrict__ A, const u16* __restrict__ Bt,
    const float* __restrict__ bias, float* __restrict__ Cf,
    u16* __restrict__ Cb, int M, int N, int K) {
  constexpr int MF = TM / 32;        // A-frags per wave
  constexpr int AINSTS = TM / 32;    // A g2l16 per wave per K-tile (8 rows each)
  __shared__ __align__(16) u16 As[2][TM * 64];
  __shared__ __align__(16) u16 Bs[2][128 * 64];
  const int tid = threadIdx.x;
  const int wid = tid >> 6;
  const int lane = tid & 63;
  const int wr = wid >> 1, wc = wid & 1;
  const int nwg = gridDim.x;
  const int id = blockIdx.x;
  const int q = nwg >> 3, r = nwg & 7;
  const int xcd = id & 7, i0 = id >> 3;
  const int swz = (xcd < r ? xcd * (q + 1) : r * (q + 1) + (xcd - r) * q) + i0;
  const int kh = (SPLITK > 1) ? (swz & (SPLITK - 1)) : 0;
  const int rest = (SPLITK > 1) ? (swz >> 1) : swz;
  const int gm = M / TM;
  const int bm = rest % gm, bn = rest / gm;
  const int Ksub = K / SPLITK;
  const int rowi = lane >> 3;                   // 0..7 within an 8-row inst
  const int gsw = ((lane & 7) ^ rowi) * 8;      // pre-swizzled k-group
  const u16* Ag = A + (size_t)(bm * TM + wid * (TM / 4) + rowi) * K + kh * Ksub + gsw;
  const u16* Bg = Bt + (size_t)(bn * 128 + wid * 32 + rowi) * K + kh * Ksub + gsw;
  auto stage = [&](int buf, int k0) {
#pragma unroll
    for (int i = 0; i < AINSTS; ++i)
      g2l16(Ag + k0 + (size_t)(8 * i) * K, As[buf] + wid * (TM / 4) * 64 + i * 512);
#pragma unroll
    for (int i = 0; i < 4; ++i)
      g2l16(Bg + k0 + (size_t)(8 * i) * K, Bs[buf] + wid * 2048 + i * 512);
  };
  f32x4 acc[MF][4] = {};
  const int fr = lane & 15;
  const int hi = lane >> 4;
  stage(0, 0);
  __syncthreads();
  for (int k0 = 0; k0 < Ksub; k0 += 64) {
    const int cur = (k0 >> 6) & 1;
    if (k0 + 64 < Ksub) stage(cur ^ 1, k0 + 64);
    short8v a[MF][2], b[4][2];
#pragma unroll
    for (int m = 0; m < MF; ++m)
#pragma unroll
      for (int kk = 0; kk < 2; ++kk) {
        const int g = (kk * 4 + hi) ^ (fr & 7);
        a[m][kk] = *(const short8v*)&As[cur][(wr * (TM / 2) + m * 16 + fr) * 64 + g * 8];
      }
#pragma unroll
    for (int n = 0; n < 4; ++n)
#pragma unroll
      for (int kk = 0; kk < 2; ++kk) {
        const int g = (kk * 4 + hi) ^ (fr & 7);
        b[n][kk] = *(const short8v*)&Bs[cur][(wc * 64 + n * 16 + fr) * 64 + g * 8];
      }
    __builtin_amdgcn_s_setprio(1);
#pragma unroll
    for (int kk = 0; kk < 2; ++kk)
#pragma unroll
      for (int m = 0; m < MF; ++m)
#pragma unroll
        for (int n = 0; n < 4; ++n)
          acc[m][n] = __builtin_amdgcn_mfma_f32_16x16x32_bf16(a[m][kk], b[n][kk], acc[m][n], 0, 0, 0);
    __builtin_amdgcn_s_setprio(0);
    __syncthreads();   // drains next-tile stage + barrier
  }
  const int row0 = bm * TM + wr * (TM / 2) + hi * 4;
  const int col0 = bn * 128 + wc * 64 + fr;
#pragma unroll
  for (int m = 0; m < MF; ++m) {
#pragma unroll
    for (int n = 0; n < 4; ++n) {
      const int col = col0 + n * 16;
      float bv = (OUT_MODE == 2) ? 0.f : bias[col];
      if (SPLITK > 1 && kh != 0) bv = 0.f;
#pragma unroll
      for (int r2 = 0; r2 < 4; ++r2) {
        const int row = row0 + m * 16 + r2;
        float v = acc[m][n][r2] + bv;
        if (GELU_ACT) v = 0.5f * v * (1.0f + erff(v * 0.70710678118f));
        size_t idx = (size_t)row * N + col;
        if (OUT_MODE == 0) Cb[idx] = f2b(v);
        else if (OUT_MODE == 1) {
          if (SPLITK > 1) atomicAdd(&Cf[idx], v);
          else Cf[idx] += v;
        } else Cf[idx] = v;
      }
    }
  }
}

// ---------------- 256^2 8-phase counted-vmcnt GEMM (LM head) ----------------
#define LDA_H(H)                                                            \
  _Pragma("unroll") for (int m = 0; m < 4; ++m)                             \
  _Pragma("unroll") for (int ks = 0; ks < 2; ++ks) {                        \
    const int row_ = wm * 128 + (H)*64 + m * 16 + fr;                       \
    const int g_ = (ks * 4 + hi) ^ (fr & 7);                                \
    a[m][ks] = *(const short8v*)&smem[cur * 16384 + row_ * 64 + g_ * 8];    \
  }
#define LDB_H(H)                                                            \
  _Pragma("unroll") for (int n = 0; n < 2; ++n)                             \
  _Pragma("unroll") for (int ks = 0; ks < 2; ++ks) {                        \
    const int row_ = wn * 64 + (H)*32 + n * 16 + fr;                        \
    const int g_ = (ks * 4 + hi) ^ (fr & 7);                                \
    b[n][ks] = *(const short8v*)&smem[32768 + cur * 16384 + row_ * 64 + g_ * 8]; \
  }
#define MFMA_CLUSTER(QA, QB)                                                \
  __builtin_amdgcn_s_barrier();                                             \
  asm volatile("s_waitcnt lgkmcnt(0)" ::: "memory");                        \
  __builtin_amdgcn_sched_barrier(0);                                        \
  __builtin_amdgcn_s_setprio(1);                                            \
  _Pragma("unroll") for (int ks = 0; ks < 2; ++ks)                          \
  _Pragma("unroll") for (int m = 0; m < 4; ++m)                             \
  _Pragma("unroll") for (int n = 0; n < 2; ++n)                             \
    acc[(QA)*4 + m][(QB)*2 + n] = __builtin_amdgcn_mfma_f32_16x16x32_bf16(  \
        a[m][ks], b[n][ks], acc[(QA)*4 + m][(QB)*2 + n], 0, 0, 0);          \
  __builtin_amdgcn_s_setprio(0);

__global__ __launch_bounds__(512, 2) void gemm256_lm(
    const u16* __restrict__ A, const u16* __restrict__ Bt,
    float* __restrict__ C, int M, int N, int K) {
  extern __shared__ __align__(16) u16 smem[];   // 128 KiB
  const int tid = threadIdx.x, wid = tid >> 6, lane = tid & 63;
  const int wm = wid >> 2, wn = wid & 3;
  const int fr = lane & 15, hi = lane >> 4;
  const int T = K / 64;
  const int nwg = gridDim.x, id = blockIdx.x;
  const int q = nwg >> 3, r = nwg & 7;
  const int xcd = id & 7, i0 = id >> 3;
  const int swz = (xcd < r ? xcd * (q + 1) : r * (q + 1) + (xcd - r) * q) + i0;
  const int gm = M / 256;
  const int bm = swz % gm, bn = swz / gm;
  const int rowA0 = bm * 256, rowB0 = bn * 256;
  const int rowoff = wid * 8 + (lane >> 3);
  const int gsw = ((lane & 7) ^ (lane >> 3)) * 8;   // pre-swizzled source group
  auto stA = [&](int qq, int tt, int bb) {
    g2l16(A + (size_t)(rowA0 + qq * 64 + rowoff) * K + tt * 64 + gsw,
          smem + bb * 16384 + qq * 4096 + wid * 512);
  };
  auto stB = [&](int qq, int tt, int bb) {
    g2l16(Bt + (size_t)(rowB0 + qq * 64 + rowoff) * K + tt * 64 + gsw,
          smem + 32768 + bb * 16384 + qq * 4096 + wid * 512);
  };
  f32x4 acc[8][4] = {};
  stA(0, 0, 0); stA(2, 0, 0);
  stB(0, 0, 0); stB(1, 0, 0); stB(2, 0, 0); stB(3, 0, 0);
  stA(1, 0, 0); stA(3, 0, 0);
  if (T > 1) {
    stA(0, 1, 1); stA(2, 1, 1);
    asm volatile("s_waitcnt vmcnt(2)" ::: "memory");
  } else {
    asm volatile("s_waitcnt vmcnt(0)" ::: "memory");
  }
  __builtin_amdgcn_s_barrier();
  for (int t = 0; t < T; ++t) {
    const int cur = t & 1, nxt = cur ^ 1;
    short8v a[4][2], b[2][2];
    // phase 0: Q(0,0)
    LDA_H(0); LDB_H(0);
    if (t + 1 < T) { stB(0, t + 1, nxt); stB(1, t + 1, nxt); }
    MFMA_CLUSTER(0, 0);
    __builtin_amdgcn_s_barrier();
    // phase 1: Q(0,1) -- A half 0 held in regs
    LDB_H(1);
    if (t + 1 < T) { stB(2, t + 1, nxt); stB(3, t + 1, nxt); }
    MFMA_CLUSTER(0, 1);
    __builtin_amdgcn_s_barrier();
    // phase 2: Q(1,1) -- B half 1 held in regs
    LDA_H(1);
    if (t + 1 < T) { stA(1, t + 1, nxt); stA(3, t + 1, nxt); }
    MFMA_CLUSTER(1, 1);
    __builtin_amdgcn_s_barrier();
    // phase 3: Q(1,0) -- A half 1 held, B half 0 re-read
    LDB_H(0);
    if (t + 2 < T) { stA(0, t + 2, cur); stA(2, t + 2, cur); }
    MFMA_CLUSTER(1, 0);
    if (t + 1 < T) {
      if (t + 2 < T) asm volatile("s_waitcnt vmcnt(2)" ::: "memory");
      else           asm volatile("s_waitcnt vmcnt(0)" ::: "memory");
      __builtin_amdgcn_s_barrier();
    }
  }
  // ---- LDS-staged coalesced epilogue: 2 chunks of 128 rows x 256 cols f32 ----
  float* lf = (float*)smem;
#pragma unroll
  for (int c = 0; c < 2; ++c) {
    __syncthreads();
    if (wm == c) {
#pragma unroll
      for (int m = 0; m < 8; ++m)
#pragma unroll
        for (int n = 0; n < 4; ++n)
#pragma unroll
          for (int rr = 0; rr < 4; ++rr)
            lf[(m * 16 + hi * 4 + rr) * 256 + wn * 64 + n * 16 + fr] =
                acc[m][n][rr];
    }
    __syncthreads();
#pragma unroll
    for (int i = 0; i < 16; ++i) {
      const int f = i * 2048 + tid * 4;
      const int rw = f >> 8, cl = f & 255;
      f32x4 v = *(const f32x4*)&lf[f];
      *(f32x4*)&C[(size_t)(rowA0 + c * 128 + rw) * N + rowB0 + cl] = v;
    }
  }
}

// ---------------- attention: split-KV partial blocks ----------------
__global__ __launch_bounds__(256) void attn_part(
    const u16* __restrict__ qkv, float* __restrict__ Op,
    float* __restrict__ Ml, u16* __restrict__ ctx) {
  __shared__ __align__(16) u16 smem[3 * 64 * 72];   // 27 KB
  u16 (*Qs)[72] = (u16(*)[72])smem;             // [64][72]
  u16 (*Ks)[72] = (u16(*)[72])(smem + 4608);    // [64][72]
  u16 (*Vs)[72] = (u16(*)[72])(smem + 9216);    // [64][72]  V^T: [d][k]
  const int job = blockIdx.x, bh = blockIdx.y;
  constexpr int qt_of[NJOB] = {0, 1, 2, 3, 4, 4, 5, 5, 6, 6, 7, 7};
  constexpr int ch_of[NJOB] = {0, 0, 0, 0, 0, 1, 0, 1, 0, 1, 0, 1};
  const int qt = qt_of[job], ch = ch_of[job];
  const int b = bh >> 4, h = bh & 15;
  const int tid = threadIdx.x, wid = tid >> 6, lane = tid & 63;
  const int fr = lane & 15, ko = (lane >> 4) * 8;
  u16 (*Ps)[72] = (u16(*)[72])(smem + wid * 1152);  // [16][72]/wave, aliases Qs
  const size_t rb = (size_t)b * S_LEN;
  const int q0 = qt * 64;
  const int hq = h * 64;
  const int t_lo = ch * 4;
  const int t_hi = (qt + 1 < t_lo + 4) ? qt + 1 : t_lo + 4;
#pragma unroll
  for (int i = 0; i < 2; ++i) {
    int e = tid + i * 256, r = e >> 3, c = (e & 7) * 8;
    *(short8v*)&Qs[r][c] = *(const short8v*)&qkv[(rb + q0 + r) * QKV_N + hq + c];
  }
  __syncthreads();
  short8v qf[2];
#pragma unroll
  for (int ks = 0; ks < 2; ++ks)
    qf[ks] = *(const short8v*)&Qs[wid * 16 + fr][ks * 32 + ko];
  f32x4 acc_o[4] = {};
  float mrow[4], lrow[4];
#pragma unroll
  for (int r = 0; r < 4; ++r) { mrow[r] = -1e30f; lrow[r] = 0.f; }
  short8v kreg[2], vreg[2];
  auto loadregs = [&](int t) {
    const int k0 = t * KVBLK;
#pragma unroll
    for (int i = 0; i < 2; ++i) {
      const int e = tid + i * 256, rr = e >> 3, cc = (e & 7) * 8;
      kreg[i] = *(const short8v*)&qkv[(rb + k0 + rr) * QKV_N + D_MODEL + hq + cc];
      vreg[i] = *(const short8v*)&qkv[(rb + k0 + rr) * QKV_N + 2 * D_MODEL + hq + cc];
    }
  };
  loadregs(t_lo);
  for (int t = t_lo; t < t_hi; ++t) {
    __syncthreads();   // Ks/Vs reads (prev iter) done
#pragma unroll
    for (int i = 0; i < 2; ++i) {
      const int e = tid + i * 256, rr = e >> 3, cc = (e & 7) * 8;
      *(short8v*)&Ks[rr][cc] = kreg[i];
#pragma unroll
      for (int j = 0; j < 8; ++j) Vs[cc + j][rr] = (u16)vreg[i][j];
    }
    __syncthreads();
    if (t + 1 < t_hi) loadregs(t + 1);   // overlap next loads with compute
    const int k0 = t * KVBLK;
    f32x4 s[4] = {};
    __builtin_amdgcn_s_setprio(1);
#pragma unroll
    for (int n = 0; n < 4; ++n)
#pragma unroll
      for (int ks = 0; ks < 2; ++ks) {
        short8v kf = *(const short8v*)&Ks[n * 16 + fr][ks * 32 + ko];
        s[n] = __builtin_amdgcn_mfma_f32_16x16x32_bf16(qf[ks], kf, s[n], 0, 0, 0);
      }
    __builtin_amdgcn_s_setprio(0);
    const int rbase = q0 + wid * 16 + (lane >> 4) * 4;
#pragma unroll
    for (int r = 0; r < 4; ++r) {
      const int row_g = rbase + r;
      float vmax = -1e30f;
#pragma unroll
      for (int n = 0; n < 4; ++n) {
        float v = s[n][r] * 0.125f;
        if (k0 + n * 16 + fr > row_g) v = -1e30f;
        s[n][r] = v;
        vmax = fmaxf(vmax, v);
      }
#pragma unroll
      for (int off = 1; off < 16; off <<= 1) vmax = fmaxf(vmax, __shfl_xor(vmax, off, 64));
      const float mnew = fmaxf(mrow[r], vmax);
      const float sc = __expf(mrow[r] - mnew);
      mrow[r] = mnew;
      float ssum = 0.f;
#pragma unroll
      for (int n = 0; n < 4; ++n) {
        float p = __expf(s[n][r] - mnew);
        s[n][r] = p;
        ssum += p;
      }
#pragma unroll
      for (int off = 1; off < 16; off <<= 1) ssum += __shfl_xor(ssum, off, 64);
      lrow[r] = lrow[r] * sc + ssum;
#pragma unroll
      for (int n = 0; n < 4; ++n) {
        acc_o[n][r] *= sc;
        Ps[(lane >> 4) * 4 + r][n * 16 + fr] = f2b(s[n][r]);
      }
    }
    __builtin_amdgcn_s_setprio(1);
#pragma unroll
    for (int ks = 0; ks < 2; ++ks) {
      short8v pf = *(const short8v*)&Ps[fr][ks * 32 + ko];
#pragma unroll
      for (int n = 0; n < 4; ++n) {
        short8v vf = *(const short8v*)&Vs[n * 16 + fr][ks * 32 + ko];
        acc_o[n] = __builtin_amdgcn_mfma_f32_16x16x32_bf16(pf, vf, acc_o[n], 0, 0, 0);
      }
    }
    __builtin_amdgcn_s_setprio(0);
  }
  if (qt < 4) {
#pragma unroll
    for (int r = 0; r < 4; ++r) {
      const int row_l = wid * 16 + (lane >> 4) * 4 + r;
      const float inv = 1.0f / lrow[r];
#pragma unroll
      for (int n = 0; n < 4; ++n)
        ctx[(rb + q0 + row_l) * D_MODEL + hq + n * 16 + fr] = f2b(acc_o[n][r] * inv);
    }
  } else {
    const size_t jb = (size_t)(bh * NJOB + job);
#pragma unroll
    for (int r = 0; r < 4; ++r) {
      const int row_l = wid * 16 + (lane >> 4) * 4 + r;
      const size_t base = (jb * 64 + row_l) * 64;
#pragma unroll
      for (int n = 0; n < 4; ++n) Op[base + n * 16 + fr] = acc_o[n][r];
      if (fr == 0) {
        Ml[jb * 128 + row_l * 2] = mrow[r];
        Ml[jb * 128 + row_l * 2 + 1] = lrow[r];
      }
    }
  }
}

// ---------------- attention: combine partials (qt>=4) -> ctx (bf16) ----------------
__global__ __launch_bounds__(256) void attn_combine(
    const float* __restrict__ Op, const float* __restrict__ Ml,
    u16* __restrict__ ctx) {
  const int qt = blockIdx.x + 4, bh = blockIdx.y;
  const int b = bh >> 4, h = bh & 15;
  const int j0 = 4 + blockIdx.x * 2;
  const size_t rb = (size_t)b * S_LEN;
  const int q0 = qt * 64, hq = h * 64;
  const size_t jb1 = (size_t)(bh * NJOB + j0);
  const size_t jb2 = jb1 + 1;
#pragma unroll
  for (int i = 0; i < 4; ++i) {
    const int idx4 = threadIdx.x + i * 256;     // float4 index 0..1023
    const int row = idx4 >> 4, c4 = (idx4 & 15) * 4;
    f32x4 o1 = *(const f32x4*)&Op[(jb1 * 64 + row) * 64 + c4];
    const float m1 = Ml[jb1 * 128 + row * 2], l1 = Ml[jb1 * 128 + row * 2 + 1];
    f32x4 o2 = *(const f32x4*)&Op[(jb2 * 64 + row) * 64 + c4];
    const float m2 = Ml[jb2 * 128 + row * 2], l2 = Ml[jb2 * 128 + row * 2 + 1];
    const float m = fmaxf(m1, m2);
    const float e1 = __expf(m1 - m), e2 = __expf(m2 - m);
    const float inv = 1.0f / (l1 * e1 + l2 * e2);
    float o[4];
#pragma unroll
    for (int j = 0; j < 4; ++j) o[j] = o1[j] * e1 + o2[j] * e2;
    uint2 pk;
    pk.x = (unsigned)f2b(o[0] * inv) | ((unsigned)f2b(o[1] * inv) << 16);
    pk.y = (unsigned)f2b(o[2] * inv) | ((unsigned)f2b(o[3] * inv) << 16);
    *(uint2*)&ctx[(rb + q0 + row) * D_MODEL + hq + c4] = pk;
  }
}

// ---------------- launch ----------------
extern "C" void kernel_launch(void* const* d_in, const int* in_sizes, int n_in,
                              void* d_out, int out_size, void* d_ws, size_t ws_size,
                              hipStream_t stream) {
  const int* x = (const int*)d_in[0];
  const float* tok_emb = (const float*)d_in[1];
  const float* wq = (const float*)d_in[2];
  const float* bq = (const float*)d_in[3];
  const float* wk = (const float*)d_in[4];
  const float* bk = (const float*)d_in[5];
  const float* wv = (const float*)d_in[6];
  const float* bv = (const float*)d_in[7];
  const float* wo = (const float*)d_in[8];
  const float* bo = (const float*)d_in[9];
  const float* ln1_g = (const float*)d_in[10];
  const float* ln1_b = (const float*)d_in[11];
  const float* w1 = (const float*)d_in[12];
  const float* b1 = (const float*)d_in[13];
  const float* w2 = (const float*)d_in[14];
  const float* b2 = (const float*)d_in[15];
  const float* ln2_g = (const float*)d_in[16];
  const float* ln2_b = (const float*)d_in[17];
  const float* lnf_g = (const float*)d_in[18];
  const float* lnf_b = (const float*)d_in[19];
  const float* lm_w = (const float*)d_in[20];

  char* w = (char*)d_ws;
  float* h    = (float*)(w);                      // 8 MB   fp32 residual
  u16*  hn    = (u16*)(w + (8ll << 20));          // 4 MB   bf16 LN out
  u16*  qkvb  = (u16*)(w + (12ll << 20));         // 12 MB  bf16 packed qkv
  u16*  cbuf  = (u16*)(w + (24ll << 20));         // 4 MB   bf16 attn ctx
  u16*  ff    = qkvb;                             // 16 MB  alias qkv+cbuf
  u16*  wqkvT = (u16*)(w + (28ll << 20));         // 36 MB  [L][3072][1024]
  u16*  woT   = (u16*)(w + (64ll << 20));         // 12 MB  [L][1024][1024]
  u16*  w1T   = (u16*)(w + (76ll << 20));         // 48 MB  [L][4096][1024]
  u16*  w2T   = (u16*)(w + (124ll << 20));        // 48 MB  [L][1024][4096]
  u16*  lmT   = (u16*)(w + (172ll << 20));        // 62.5MB [32000][1024]
  float* bqkv = (float*)(w + (235ll << 20));      // 72 KB  [L][3072]
  float* Op   = (float*)(w + (236ll << 20));      // 12 MB  attn partial O
  float* Ml   = (float*)(w + (249ll << 20));      // 0.4 MB attn partial m,l

  transpose_all<<<52864, 256, 0, stream>>>(
      wq, wk, wv, wo, w1, w2, lm_w, wqkvT, woT, w1T, w2T, lmT);
  pack_qkv_bias<<<L_NUM * QKV_N / 256, 256, 0, stream>>>(bq, bk, bv, bqkv);

  embed_kernel<<<ROWS, 256, 0, stream>>>(x, tok_emb, h);

  const size_t DD = (size_t)D_MODEL * D_MODEL;
  const size_t DDF = (size_t)D_MODEL * DF_DIM;
  const long QS = (long)QKV_N * D_MODEL;
  const int nQKV = (ROWS / 64) * (QKV_N / 128);       // 768  (3/CU)
  const int nPRJ = 2 * (ROWS / 64) * (D_MODEL / 128); // 512  (2/CU, split-K)
  const int nFF1 = (ROWS / 128) * (DF_DIM / 128);     // 512  (2/CU, TM=128)
  const int nFF2 = 2 * (ROWS / 64) * (D_MODEL / 128); // 512  (2/CU, split-K)
  for (int l = 0; l < L_NUM; ++l) {
    layernorm_kernel<<<ROWS / 4, 256, 0, stream>>>(h, ln1_g + l * D_MODEL, ln1_b + l * D_MODEL, hn);
    gemm_bf16<64, 0, false, 1><<<nQKV, 256, 0, stream>>>(
        hn, wqkvT + (size_t)l * QS, bqkv + l * QKV_N, nullptr, qkvb,
        ROWS, QKV_N, D_MODEL);
    attn_part<<<dim3(NJOB, B_SZ * H_NUM), 256, 0, stream>>>(qkvb, Op, Ml, cbuf);
    attn_combine<<<dim3(4, B_SZ * H_NUM), 256, 0, stream>>>(Op, Ml, cbuf);
    gemm_bf16<64, 1, false, 2><<<nPRJ, 256, 0, stream>>>(
        cbuf, woT + l * DD, bo + l * D_MODEL, h, nullptr, ROWS, D_MODEL, D_MODEL);
    layernorm_kernel<<<ROWS / 4, 256, 0, stream>>>(h, ln2_g + l * D_MODEL, ln2_b + l * D_MODEL, hn);
    gemm_bf16<128, 0, true, 1><<<nFF1, 256, 0, stream>>>(
        hn, w1T + l * DDF, b1 + l * DF_DIM, nullptr, ff, ROWS, DF_DIM, D_MODEL);
    gemm_bf16<64, 1, false, 2><<<nFF2, 256, 0, stream>>>(
        ff, w2T + l * DDF, b2 + l * D_MODEL, h, nullptr, ROWS, D_MODEL, DF_DIM);
  }
  layernorm_kernel<<<ROWS / 4, 256, 0, stream>>>(h, lnf_g, lnf_b, hn);

  hipFuncSetAttribute((const void*)gemm256_lm,
                      hipFuncAttributeMaxDynamicSharedMemorySize, 131072);
  const int nLM = (ROWS / 256) * (V_SIZE / 256);   // 8 * 125 = 1000
  gemm256_lm<<<nLM, 512, 131072, stream>>>(
      hn, lmT, (float*)d_out, ROWS, V_SIZE, D_MODEL);
}